// Round 1
// 1512.136 us; speedup vs baseline: 1.0066x; 1.0066x over previous
//
#include <hip/hip_runtime.h>

// Problem dims (fixed by setup_inputs)
constexpr int NB = 1024;   // batch
constexpr int NT = 512;    // time steps
constexpr int NI = 100;    // input dim
constexpr int NH = 150;    // hidden dim
constexpr int NO = 3;      // output classes
constexpr int KP = 256;    // padded K: [0,150)=h, [150,152)=0, [152,252)=x, [252,256)=0
constexpr int XOFF = 152;  // x offset inside hx row (16B aligned)
constexpr int ROWS = 4;    // batch rows per workgroup
constexpr int NCH = 8;     // 4-wide k-chunks per thread (64 chunks total / 8 k-groups)

// DPP-based add: v += shuffled(v). CTRL: 0xB1 = quad_perm xor1, 0x4E = quad_perm xor2,
// 0x141 = row_half_mirror (lane^7 within each 8 => completes the 8-lane sum after xor1/xor2).
template<int CTRL>
__device__ __forceinline__ float dpp_add(float v) {
    int t = __builtin_amdgcn_update_dpp(0, __float_as_int(v), CTRL, 0xF, 0xF, true);
    return v + __int_as_float(t);
}

// Layout: block = 512 threads = 8 waves. lane = tid&63.
//   kg = lane&7   : k-group (owns chunks c = kg + 8i, i<8)
//   oq = lane>>3  : 0..7;  oi = wave*8 + oq in [0,64)
//   thread computes partial dots for o in {oi, oi+64, oi+128} (o<153; 150..152 = fc rows)
//   and all 4 batch rows.  W held in 96 regs/thread.  DPP butterfly over kg bits reduces.
// Double-buffered hx => ONE barrier per step. Phase-B writes spread over kg<4 lanes.
__global__ __launch_bounds__(512, 2)
void rnn_fused(const float* __restrict__ x, const float* __restrict__ h0,
               const float* __restrict__ g, const float* __restrict__ Wih,
               const float* __restrict__ Whh, const float* __restrict__ Wfc,
               float* __restrict__ out, float* __restrict__ hidden,
               float* __restrict__ logits)
{
    __shared__ __align__(16) float hx[2][ROWS * KP];  // 2 x 4KB: [h | pad | x | pad] per row
    __shared__ float lg[2][ROWS][4];                  // logits staging, double-buffered

    const int tid  = threadIdx.x;
    const int lane = tid & 63;
    const int wv   = tid >> 6;
    const int kg   = lane & 7;
    const int oq   = lane >> 3;
    const int oi   = wv * 8 + oq;
    const int row0 = blockIdx.x * ROWS;

    // ---- load this thread's W slice into registers ----
    float Wreg[3][NCH][4];
#pragma unroll
    for (int j = 0; j < 3; ++j) {
        const int o = oi + 64 * j;
#pragma unroll
        for (int i = 0; i < NCH; ++i) {
#pragma unroll
            for (int q = 0; q < 4; ++q) {
                const int k = 4 * (kg + 8 * i) + q;
                float v = 0.f;
                if (o < NH) {
                    if (k < NH) v = Whh[o * NH + k];
                    else if (k >= XOFF && k < XOFF + NI) v = Wih[o * NI + (k - XOFF)];
                } else if (o < NH + NO) {
                    if (k < NH) v = Wfc[(o - NH) * NH + k];
                }
                Wreg[j][i][q] = v;
            }
        }
    }

    // ---- init hx[0]: h0, x(t=0); zero pads in BOTH buffers ----
    for (int e = tid; e < ROWS * NH; e += 512) {
        int b = e / NH, k = e - b * NH;
        hx[0][b * KP + k] = h0[(row0 + b) * NH + k];
    }
    for (int e = tid; e < ROWS * NI; e += 512) {
        int b = e / NI, i = e - b * NI;
        hx[0][b * KP + XOFF + i] = x[((size_t)(row0 + b) * NT + 0) * NI + i];
    }
    if (tid < 2 * ROWS * 6) {
        int u = tid; int f = u / (ROWS * 6); u -= f * (ROWS * 6);
        int b = u / 6, z = u - b * 6;
        int k = (z < 2) ? (NH + z) : (252 + z - 2);
        hx[f][b * KP + k] = 0.f;
    }
    __syncthreads();

    // ---- hoisted loop-invariant bases ----
    const int xb = tid / 25, xq = tid - xb * 25;                        // tid<100 stager ids
    const float* xrow = x + ((size_t)(row0 + (xb & 3)) * NT) * NI + 4 * xq; // x row base
    float* hidb = hidden + ((size_t)(row0 + (kg & 3)) * NT) * NH;       // used when kg<ROWS
    const float* grow = g + ((size_t)(row0 + (tid & 3)) * NT) * NO;     // used when tid<ROWS
    const size_t emitb = ((size_t)(row0 + (tid & 3)) * NT) * NO;        // used when tid<ROWS

    auto step = [&](int t, const float* __restrict__ cur, float* __restrict__ nxt,
                    float (*__restrict__ lgb)[4]) {
        // prefetch x[t+1] into regs (hides HBM latency under the compute phase)
        float4 xp = make_float4(0.f, 0.f, 0.f, 0.f);
        const bool do_x = (tid < 100) && (t < NT - 1);
        if (do_x) xp = *reinterpret_cast<const float4*>(xrow + (size_t)(t + 1) * NI);
        // prefetch g[t-1] for the emit phase
        float g0 = 0.f, g1 = 0.f, g2 = 0.f;
        const bool do_e = (tid < ROWS) && (t >= 1);
        if (do_e) {
            const float* gp = grow + (size_t)(t - 1) * NO;
            g0 = gp[0]; g1 = gp[1]; g2 = gp[2];
        }

        // ---- partial dot products over this thread's k-chunks ----
        const float4* cur4 = reinterpret_cast<const float4*>(cur);
        float acc[3][ROWS];
#pragma unroll
        for (int j = 0; j < 3; ++j)
#pragma unroll
            for (int b = 0; b < ROWS; ++b) acc[j][b] = 0.f;

#pragma unroll
        for (int i = 0; i < NCH; ++i) {
            const int c = kg + 8 * i;
#pragma unroll
            for (int b = 0; b < ROWS; ++b) {
                const float4 hv = cur4[b * (KP / 4) + c];
#pragma unroll
                for (int j = 0; j < 3; ++j) {
                    acc[j][b] += Wreg[j][i][0] * hv.x;
                    acc[j][b] += Wreg[j][i][1] * hv.y;
                    acc[j][b] += Wreg[j][i][2] * hv.z;
                    acc[j][b] += Wreg[j][i][3] * hv.w;
                }
            }
        }

        // ---- DPP butterfly across the 8 k-groups (VALU pipe, no LDS round-trip) ----
#pragma unroll
        for (int j = 0; j < 3; ++j)
#pragma unroll
            for (int b = 0; b < ROWS; ++b) {
                float v = acc[j][b];
                v = dpp_add<0xB1>(v);   // xor 1
                v = dpp_add<0x4E>(v);   // xor 2
                v = dpp_add<0x141>(v);  // xor 4 (row_half_mirror after quad sums)
                acc[j][b] = v;
            }

        // ---- phase B: lane kg==b writes row b (4x more writers than kg==0 scheme) ----
        if (kg < ROWS) {
            const int b = kg;
#pragma unroll
            for (int j = 0; j < 3; ++j) {
                const int o = oi + 64 * j;
                if (o < NH) {
                    if (t < NT) {
                        float v = fmaxf(acc[j][b], 0.f);
                        nxt[b * KP + o] = v;
                        hidb[(size_t)t * NH + o] = v;
                    }
                } else if (o < NH + NO) {
                    lgb[b][o - NH] = acc[j][b];
                }
            }
        }
        // stage prefetched x[t+1] into the NEXT buffer
        if (do_x) *reinterpret_cast<float4*>(nxt + xb * KP + XOFF + 4 * xq) = xp;
        __syncthreads();  // single barrier: nxt fully written, cur free for overwrite

        // ---- emit out/logits for time t-1 (logits lag one step by construction) ----
        if (do_e) {
            float l0 = lgb[tid][0], l1 = lgb[tid][1], l2 = lgb[tid][2];
            float s0 = l0 + g0, s1 = l1 + g1, s2 = l2 + g2;
            int am = 0; float best = s0;
            if (s1 > best) { best = s1; am = 1; }
            if (s2 > best) { am = 2; }
            size_t base = emitb + (size_t)(t - 1) * NO;
            out[base + 0] = (am == 0) ? 1.f : 0.f;
            out[base + 1] = (am == 1) ? 1.f : 0.f;
            out[base + 2] = (am == 2) ? 1.f : 0.f;
            logits[base + 0] = l0;
            logits[base + 1] = l1;
            logits[base + 2] = l2;
        }
    };

    // t-loop unrolled x2: LDS buffer selection is compile-time (immediate ds offsets)
    for (int t = 0; t < NT; t += 2) {
        step(t,     hx[0], hx[1], lg[0]);
        step(t + 1, hx[1], hx[0], lg[1]);
    }
    step(NT, hx[0], hx[1], lg[0]);  // tail: fc of h[NT-1] + final emit
}

extern "C" void kernel_launch(void* const* d_in, const int* in_sizes, int n_in,
                              void* d_out, int out_size, void* d_ws, size_t ws_size,
                              hipStream_t stream) {
    const float* x   = (const float*)d_in[0];
    const float* h0  = (const float*)d_in[1];
    const float* g   = (const float*)d_in[2];
    const float* Wih = (const float*)d_in[3];
    const float* Whh = (const float*)d_in[4];
    const float* Wfc = (const float*)d_in[5];

    float* out    = (float*)d_out;
    float* hidden = out + (size_t)NB * NT * NO;
    float* logits = hidden + (size_t)NB * NT * NH;

    hipLaunchKernelGGL(rnn_fused, dim3(NB / ROWS), dim3(512), 0, stream,
                       x, h0, g, Wih, Whh, Wfc, out, hidden, logits);
}